// Round 9
// baseline (194.167 us; speedup 1.0000x reference)
//
#include <hip/hip_runtime.h>
#include <math.h>

// R8 skeleton (proven 85 us, absmax 0.0039) + three changes:
//  1) sigmoid rcp: v_rcp_f32 (16-cyc trans) -> bit-seed + 2 Newton (packed VALU,
//     rel err ~6e-6). Trans issue per sigmoid halves; serial latency 50->30 cyc.
//  2) float2 packing across the 2 rays/thread: v_pk_fma/mul/add for all sigmoid
//     glue + accumulators + P2 arithmetic. Selects stay scalar per ray.
//  3) fused min/max+normalize via R7-validated counter-spin: 1024 blocks x
//     33.3 KB LDS = exactly 4 blocks/CU co-resident -> spin is deadlock-free.
//     Removes norm kernel + 1 memset node; rdep never leaves registers.

#define NT 64
#define PTS 64
#define NRAYS (2*256*256)
#define NBLK (NRAYS/128)          // 1024 blocks, 2 rays/thread
#define NEARV 0.1f
#define STEPV (1.9f/63.0f)
#define FAR63 (0.1f + 63.0f*(1.9f/63.0f))
#define NL2E (-1.4426950408889634f)

typedef float v2f __attribute__((ext_vector_type(2)));

extern "C" __device__ float __ocml_native_exp2_f32(float);

__device__ __forceinline__ v2f exp2v(v2f a) {
    v2f r;
    r.x = __ocml_native_exp2_f32(a.x);
    r.y = __ocml_native_exp2_f32(a.y);
    return r;
}
// reciprocal of positive normal floats: bit seed (~3.4% err) + 2 NR -> ~6e-6 rel
__device__ __forceinline__ v2f rcpv(v2f u) {
    v2f y;
    y.x = __int_as_float(0x7EF311C3 - __float_as_int(u.x));
    y.y = __int_as_float(0x7EF311C3 - __float_as_int(u.y));
    y = y * (2.0f - u * y);
    y = y * (2.0f - u * y);
    return y;
}
__device__ __forceinline__ v2f sigv(v2f arg) {   // sigmoid; arg = -x*log2e
    v2f a;                                        // clamp: keep e finite (inf -> NR NaN)
    a.x = fminf(arg.x, 126.0f);
    a.y = fminf(arg.y, 126.0f);
    return rcpv(exp2v(a) + 1.0f);
}

__global__ __launch_bounds__(NT) void nerf_main(
    const float* __restrict__ tm, const float* __restrict__ wq,
    float* __restrict__ out, unsigned int* __restrict__ cnt,
    float* __restrict__ part)
{
    __shared__ float fd[2][PTS + 1][NT];   // per-ray fine depths + junk pad row
    const int tid = threadIdx.x;
    const int r0 = blockIdx.x * 128 + tid;
    const int r1 = r0 + 64;

    float bAs[2][4], sAs[2][4];
    int bb_[2], nn_[2];
    #pragma unroll
    for (int q = 0; q < 2; q++) {
        int r = (q == 0) ? r0 : r1;
        int b = r >> 16, n = r & 65535;
        bb_[q] = b; nn_[q] = n;
        int i = n >> 8, j = n & 255;
        float cx = (1.0f + (float)j * (-2.0f/255.0f)) * (1.0f/4.2f);
        float cy = (1.0f + (float)i * (-2.0f/255.0f)) * (1.0f/4.2f);
        const float* tmb = tm + b*12;
        float dx = tmb[0]*cx + tmb[1]*cy + tmb[2];
        float dy = tmb[4]*cx + tmb[5]*cy + tmb[6];
        float dz = tmb[8]*cx + tmb[9]*cy + tmb[10];
        float ox = tmb[3], oy = tmb[7], oz = tmb[11];
        #pragma unroll
        for (int c = 0; c < 4; c++) {
            float s  = dx*wq[0*4+c] + dy*wq[1*4+c] + dz*wq[2*4+c];
            float bv = ox*wq[0*4+c] + oy*wq[1*4+c] + oz*wq[2*4+c]
                     + dx*wq[3*4+c] + dy*wq[4*4+c] + dz*wq[5*4+c];
            sAs[q][c] = s * NL2E;
            bAs[q][c] = bv * NL2E;
        }
    }
    v2f bA[4], sA[4];
    #pragma unroll
    for (int c = 0; c < 4; c++) {
        bA[c].x = bAs[0][c]; bA[c].y = bAs[1][c];
        sA[c].x = sAs[0][c]; sA[c].y = sAs[1][c];
    }

    // ---- phase 1: coarse march, packed ----
    v2f T = {1.0f, 1.0f}, S = {0.0f, 0.0f};
    v2f A0 = {0.0f, 0.0f}, A1 = {0.0f, 0.0f}, A2 = {0.0f, 0.0f};
    #pragma unroll 4
    for (int p = 0; p < PTS; p++) {
        float d = fmaf((float)p, STEPV, NEARV);
        v2f op = sigv(bA[0] + d*sA[0]);
        v2f v0 = sigv(bA[1] + d*sA[1]);
        v2f v1 = sigv(bA[2] + d*sA[2]);
        v2f v2_ = sigv(bA[3] + d*sA[3]);
        v2f w = op * T;
        A0 += w * v0; A1 += w * v1; A2 += w * v2_;
        S += w + 1e-5f;
        T *= (1.0f - op);
    }
    out[(bb_[0]*3+0)*65536 + nn_[0]] = A0.x;
    out[(bb_[0]*3+1)*65536 + nn_[0]] = A1.x;
    out[(bb_[0]*3+2)*65536 + nn_[0]] = A2.x;
    out[(bb_[1]*3+0)*65536 + nn_[1]] = A0.y;
    out[(bb_[1]*3+1)*65536 + nn_[1]] = A1.y;
    out[(bb_[1]*3+2)*65536 + nn_[1]] = A2.y;

    // ---- phase 2: branchless sampling machines, packed arith / scalar selects ----
    v2f Sinv = rcpv(S);
    v2f op0 = sigv(bA[0] + NEARV*sA[0]);
    v2f T2 = 1.0f - op0;
    v2f c_lo = {0.0f, 0.0f};
    v2f c_hi = (op0 + 1e-5f) * Sinv;       // cdf[0]
    int ind0 = 0, ind1 = 0, k0 = 1, k1 = 1;
    v2f binp = {NEARV, NEARV};             // bin_0 == NEAR always
    #pragma unroll 1
    for (int it = 0; it < 2*PTS; it++) {
        float u0 = (float)k0 * 0.015625f;  // exact k/64
        float u1 = (float)k1 * 0.015625f;
        bool adv0 = (ind0 < PTS) && (c_hi.x <= u0);   // searchsorted 'right'
        bool adv1 = (ind1 < PTS) && (c_hi.y <= u1);
        float dn0 = fmaf((float)min(ind0 + 1, 63), STEPV, NEARV);
        float dn1 = fmaf((float)min(ind1 + 1, 63), STEPV, NEARV);
        v2f dn = {dn0, dn1};
        v2f opn = sigv(bA[0] + dn*sA[0]);
        v2f nch = c_hi + (opn*T2 + 1e-5f) * Sinv;
        v2f nT2 = T2 * (1.0f - opn);
        v2f d0 = {fmaf((float)(ind0 - 1), STEPV, NEARV),
                  fmaf((float)(ind1 - 1), STEPV, NEARV)};
        v2f den = c_hi - c_lo;
        den.x = (den.x < 1e-8f) ? 1.0f : den.x;       // ref guard
        den.y = (den.y < 1e-8f) ? 1.0f : den.y;
        v2f uu = {u0, u1};
        v2f tt = (uu - c_lo) * rcpv(den);             // den in [1e-8,1] U {1}: normal
        tt.x = fminf(fmaxf(tt.x, 0.0f), 1.0f);
        tt.y = fminf(fmaxf(tt.y, 0.0f), 1.0f);
        v2f bin = tt*STEPV + d0;
        bin.x = (ind0 <= 0) ? NEARV : ((ind0 >= PTS) ? FAR63 : bin.x);
        bin.y = (ind1 <= 0) ? NEARV : ((ind1 >= PTS) ? FAR63 : bin.y);
        v2f fdep = 0.5f * (binp + bin);
        int w0i = adv0 ? PTS : min(k0 - 1, PTS);      // pad row on advance
        int w1i = adv1 ? PTS : min(k1 - 1, PTS);
        fd[0][w0i][tid] = fdep.x;                     // unconditional ds_write
        fd[1][w1i][tid] = fdep.y;
        c_lo.x = adv0 ? c_hi.x : c_lo.x;  c_hi.x = adv0 ? nch.x : c_hi.x;
        T2.x   = adv0 ? nT2.x  : T2.x;    binp.x = adv0 ? binp.x : bin.x;
        ind0 += adv0 ? 1 : 0;             k0 += adv0 ? 0 : 1;
        c_lo.y = adv1 ? c_hi.y : c_lo.y;  c_hi.y = adv1 ? nch.y : c_hi.y;
        T2.y   = adv1 ? nT2.y  : T2.y;    binp.y = adv1 ? binp.y : bin.y;
        ind1 += adv1 ? 1 : 0;             k1 += adv1 ? 0 : 1;
    }

    // ---- phase 3: branchless merge, packed sigmoids / scalar decisions ----
    v2f T3 = {1.0f, 1.0f}, sw = {0.0f, 0.0f};
    v2f F0 = {0.0f, 0.0f}, F1 = {0.0f, 0.0f}, F2 = {0.0f, 0.0f}, rd = {0.0f, 0.0f};
    int pc0 = 0, pc1 = 0, pf0 = 0, pf1 = 0;
    float dc0 = NEARV, dc1 = NEARV;
    float cur0 = fd[0][0][tid], cur1 = fd[1][0][tid];
    float nxt0 = fd[0][1][tid], nxt1 = fd[1][1][tid];
    #pragma unroll 1
    for (int it = 0; it < 2*PTS; it++) {
        float dfv0 = (pf0 < PTS) ? cur0 : 3.0e38f;
        bool tc0 = (pc0 < PTS) && (dc0 <= dfv0);      // ties -> coarse (stable)
        float d_0 = tc0 ? dc0 : dfv0;
        pc0 += tc0 ? 1 : 0;  dc0 = fmaf((float)pc0, STEPV, NEARV);
        pf0 += tc0 ? 0 : 1;  cur0 = tc0 ? cur0 : nxt0;
        nxt0 = fd[0][min(pf0 + 1, PTS)][tid];
        float dfv1 = (pf1 < PTS) ? cur1 : 3.0e38f;
        bool tc1 = (pc1 < PTS) && (dc1 <= dfv1);
        float d_1 = tc1 ? dc1 : dfv1;
        pc1 += tc1 ? 1 : 0;  dc1 = fmaf((float)pc1, STEPV, NEARV);
        pf1 += tc1 ? 0 : 1;  cur1 = tc1 ? cur1 : nxt1;
        nxt1 = fd[1][min(pf1 + 1, PTS)][tid];
        v2f d2 = {d_0, d_1};
        v2f op = sigv(bA[0] + d2*sA[0]);
        v2f v0 = sigv(bA[1] + d2*sA[1]);
        v2f v1 = sigv(bA[2] + d2*sA[2]);
        v2f v2_ = sigv(bA[3] + d2*sA[3]);
        v2f w = op * T3;
        F0 += w * v0; F1 += w * v1; F2 += w * v2_;
        sw += w;
        rd += w * d2;
        T3 *= (1.0f - op);
    }
    out[393216 + (bb_[0]*3+0)*65536 + nn_[0]] = F0.x;
    out[393216 + (bb_[0]*3+1)*65536 + nn_[0]] = F1.x;
    out[393216 + (bb_[0]*3+2)*65536 + nn_[0]] = F2.x;
    out[393216 + (bb_[1]*3+0)*65536 + nn_[1]] = F0.y;
    out[393216 + (bb_[1]*3+1)*65536 + nn_[1]] = F1.y;
    out[393216 + (bb_[1]*3+2)*65536 + nn_[1]] = F2.y;

    v2f fop;
    fop.x = fminf(fmaxf(sw.x, 0.0f), 1.0f);
    fop.y = fminf(fmaxf(sw.y, 0.0f), 1.0f);
    v2f rdep = rd + (1.0f - fop) * 2.0f;   // d_all.max() == 2.0 exactly

    // ---- fused min/max + normalize (counter-spin; 4 blocks/CU co-resident) ----
    float mn = fminf(rdep.x, rdep.y), mx = fmaxf(rdep.x, rdep.y);
    #pragma unroll
    for (int m = 32; m >= 1; m >>= 1) {
        mn = fminf(mn, __shfl_xor(mn, m, 64));
        mx = fmaxf(mx, __shfl_xor(mx, m, 64));
    }
    if (tid == 0) {
        part[2*blockIdx.x]     = mn;
        part[2*blockIdx.x + 1] = mx;
        __hip_atomic_fetch_add(cnt, 1u, __ATOMIC_RELEASE, __HIP_MEMORY_SCOPE_AGENT);
        while (__hip_atomic_load(cnt, __ATOMIC_ACQUIRE, __HIP_MEMORY_SCOPE_AGENT) < NBLK)
            __builtin_amdgcn_s_sleep(8);
    }
    __syncthreads();                       // single wave: reconverge + order
    mn = 3.4e38f; mx = -3.4e38f;
    #pragma unroll 1
    for (int q = tid; q < NBLK; q += NT) { // 16 pairs/lane, L2-hit
        float pmn = __hip_atomic_load(&part[2*q],     __ATOMIC_RELAXED, __HIP_MEMORY_SCOPE_AGENT);
        float pmx = __hip_atomic_load(&part[2*q + 1], __ATOMIC_RELAXED, __HIP_MEMORY_SCOPE_AGENT);
        mn = fminf(mn, pmn);
        mx = fmaxf(mx, pmx);
    }
    #pragma unroll
    for (int m = 32; m >= 1; m >>= 1) {
        mn = fminf(mn, __shfl_xor(mn, m, 64));
        mx = fmaxf(mx, __shfl_xor(mx, m, 64));
    }
    float inv = __builtin_amdgcn_rcpf(mx - mn);
    out[786432 + r0] = (rdep.x - mn) * inv;
    out[786432 + r1] = (rdep.y - mn) * inv;
}

extern "C" void kernel_launch(void* const* d_in, const int* in_sizes, int n_in,
                              void* d_out, int out_size, void* d_ws, size_t ws_size,
                              hipStream_t stream) {
    (void)in_sizes; (void)n_in; (void)out_size; (void)ws_size;
    const float* tm = (const float*)d_in[0];
    const float* wq = (const float*)d_in[1];
    float* out = (float*)d_out;
    unsigned int* cnt = (unsigned int*)d_ws;
    float* part = (float*)((char*)d_ws + 128);   // keep off the counter's line
    hipMemsetAsync(d_ws, 0, 4, stream);          // zero the arrival counter
    nerf_main<<<NBLK, NT, 0, stream>>>(tm, wq, out, cnt, part);
}